// Round 1
// baseline (1247.514 us; speedup 1.0000x reference)
//
#include <hip/hip_runtime.h>
#include <math.h>

namespace {
constexpr int kB  = 16;
constexpr int kD  = 512;
constexpr int kL  = 3000;
constexpr int kNE = 1024;
constexpr int BM  = 64;    // l-tile
constexpr int BN  = 256;   // n-tile per outer iteration (4 iters cover NE)
constexpr int BK  = 16;    // k-chunk staged in LDS
constexpr int NT  = 256;   // threads per block
constexpr int N_ZQ  = kB * kD * kL;  // 24576000
constexpr int N_IND = kB * kL;       // 48000
}

__global__ void vq_zero_ws(double* ws) { ws[0] = 0.0; }

__global__ __launch_bounds__(NT, 4) void vq_main(
    const float* __restrict__ z, const float* __restrict__ W,
    float* __restrict__ zq, float* __restrict__ ind, double* __restrict__ lossws)
{
  __shared__ union {
    struct { float A[BK][BM]; float Bt[BK][BN]; } s;   // 4 KB + 16 KB
    struct { float rv[BM][33]; int ri[BM][33]; } r;    // padded: conflict-free
  } u;
  __shared__ int    bidx_s[BM];
  __shared__ double lred[NT];

  const int tid = threadIdx.x;
  const int l0  = blockIdx.x * BM;
  const int b   = blockIdx.y;
  const size_t zb = (size_t)b * (size_t)kD * (size_t)kL;

  const int tx = tid & 31;   // n-group 0..31  -> n cols tx*4+{0..3}, 128+tx*4+{0..3}
  const int ty = tid >> 5;   // m-group 0..7   -> m rows ty*4+{0..3}, 32+ty*4+{0..3}

  float bv[8];
  int   bi[8];
#pragma unroll
  for (int i = 0; i < 8; ++i) { bv[i] = -INFINITY; bi[i] = 0; }

  // A staging map: each thread loads one float4 of a k-row (64 contiguous l per row)
  const int a_k = tid >> 4;            // 0..15
  const int a_m = (tid & 15) << 2;     // 0,4,...,60  (kL boundary is float4-aligned: 3000-2944=56)
  const bool a_ok = (l0 + a_m) < kL;
  const float* aptr = z + zb + (size_t)a_k * kL + (l0 + a_m);

  for (int n0 = 0; n0 < kNE; n0 += BN) {
    float acc[8][8];
#pragma unroll
    for (int i = 0; i < 8; ++i)
#pragma unroll
      for (int j = 0; j < 8; ++j) acc[i][j] = 0.f;

    const float* wrow = W + (size_t)(n0 + tid) * kD;  // one codebook row per thread

    for (int k0 = 0; k0 < kD; k0 += BK) {
      __syncthreads();
      // ---- stage A (z) : [BK][BM], coalesced float4 ----
      {
        float4 av = make_float4(0.f, 0.f, 0.f, 0.f);
        if (a_ok) av = *(const float4*)(aptr + (size_t)k0 * kL);
        *(float4*)(&u.s.A[a_k][a_m]) = av;
      }
      // ---- stage B (W) transposed to k-major: Bt[kk][n] ----
      {
        const float* wr = wrow + k0;
        float4 w0 = *(const float4*)(wr);
        float4 w1 = *(const float4*)(wr + 4);
        u.s.Bt[0][tid] = w0.x;  u.s.Bt[1][tid] = w0.y;
        u.s.Bt[2][tid] = w0.z;  u.s.Bt[3][tid] = w0.w;
        u.s.Bt[4][tid] = w1.x;  u.s.Bt[5][tid] = w1.y;
        u.s.Bt[6][tid] = w1.z;  u.s.Bt[7][tid] = w1.w;
        float4 w2 = *(const float4*)(wr + 8);
        float4 w3 = *(const float4*)(wr + 12);
        u.s.Bt[8][tid]  = w2.x; u.s.Bt[9][tid]  = w2.y;
        u.s.Bt[10][tid] = w2.z; u.s.Bt[11][tid] = w2.w;
        u.s.Bt[12][tid] = w3.x; u.s.Bt[13][tid] = w3.y;
        u.s.Bt[14][tid] = w3.z; u.s.Bt[15][tid] = w3.w;
      }
      __syncthreads();
      // ---- compute: 16 k-steps x 64 FMA ----
#pragma unroll
      for (int kk = 0; kk < BK; ++kk) {
        float4 a0 = *(const float4*)(&u.s.A[kk][ty << 2]);
        float4 a1 = *(const float4*)(&u.s.A[kk][(ty << 2) + 32]);
        float4 b0 = *(const float4*)(&u.s.Bt[kk][tx << 2]);
        float4 b1 = *(const float4*)(&u.s.Bt[kk][(tx << 2) + 128]);
        float am[8] = {a0.x, a0.y, a0.z, a0.w, a1.x, a1.y, a1.z, a1.w};
        float bn[8] = {b0.x, b0.y, b0.z, b0.w, b1.x, b1.y, b1.z, b1.w};
#pragma unroll
        for (int i = 0; i < 8; ++i)
#pragma unroll
          for (int j = 0; j < 8; ++j)
            acc[i][j] = fmaf(am[i], bn[j], acc[i][j]);
      }
    }
    // ---- running argmax update (ascending n within thread -> strict > keeps lowest idx) ----
#pragma unroll
    for (int j = 0; j < 8; ++j) {
      const int n = n0 + ((j < 4) ? (tx * 4 + j) : (128 + tx * 4 + (j - 4)));
#pragma unroll
      for (int i = 0; i < 8; ++i) {
        if (acc[i][j] > bv[i]) { bv[i] = acc[i][j]; bi[i] = n; }
      }
    }
  }

  // ---- cross-thread argmax reduction (16..: 32 tx columns share each m row) ----
  __syncthreads();  // staging LDS dead -> reuse as reduction arrays
#pragma unroll
  for (int i = 0; i < 8; ++i) {
    const int m = (i < 4) ? ((ty << 2) + i) : (32 + (ty << 2) + (i - 4));
    u.r.rv[m][tx] = bv[i];
    u.r.ri[m][tx] = bi[i];
  }
  __syncthreads();
  if (tid < BM) {
    float best = u.r.rv[tid][0];
    int   idx  = u.r.ri[tid][0];
    for (int t = 1; t < 32; ++t) {
      float v  = u.r.rv[tid][t];
      int   ix = u.r.ri[tid][t];
      if (v > best || (v == best && ix < idx)) { best = v; idx = ix; }
    }
    bidx_s[tid] = idx;
    if (l0 + tid < kL) ind[b * kL + l0 + tid] = (float)idx;  // ind as float32
  }
  __syncthreads();

  // ---- epilogue: z_q gather + f64 loss partial ----
  const int mvalid = kL - l0;  // >= 56, boundary float4-aligned
  double lsum = 0.0;
#pragma unroll 4
  for (int r = 0; r < (BM * kD) / (NT * 4); ++r) {  // 32 reps, float4 per thread
    const int flat = r * NT + tid;
    const int d  = flat >> 4;
    const int m4 = (flat & 15) << 2;
    if (m4 < mvalid) {
      const size_t zi = zb + (size_t)d * kL + (l0 + m4);
      float4 zv = *(const float4*)(z + zi);
      float4 wv;
      wv.x = W[(size_t)bidx_s[m4 + 0] * kD + d];
      wv.y = W[(size_t)bidx_s[m4 + 1] * kD + d];
      wv.z = W[(size_t)bidx_s[m4 + 2] * kD + d];
      wv.w = W[(size_t)bidx_s[m4 + 3] * kD + d];
      *(float4*)(zq + zi) = wv;
      const float dx = wv.x - zv.x, dy = wv.y - zv.y;
      const float dz2 = wv.z - zv.z, dw = wv.w - zv.w;
      lsum += (double)dx * dx + (double)dy * dy + (double)dz2 * dz2 + (double)dw * dw;
    }
  }
  lred[tid] = lsum;
  __syncthreads();
  if (tid == 0) {
    double s = 0.0;
    for (int t = 0; t < NT; ++t) s += lred[t];
    atomicAdd(lossws, s);
  }
}

__global__ void vq_finish(const double* __restrict__ ws, float* __restrict__ out) {
  out[0] = (float)(ws[0] * 2.25 / (double)N_ZQ);
}

extern "C" void kernel_launch(void* const* d_in, const int* in_sizes, int n_in,
                              void* d_out, int out_size, void* d_ws, size_t ws_size,
                              hipStream_t stream) {
  const float* z = (const float*)d_in[0];
  const float* W = (const float*)d_in[1];
  float* out = (float*)d_out;
  double* ws = (double*)d_ws;

  vq_zero_ws<<<1, 1, 0, stream>>>(ws);
  dim3 grid((kL + BM - 1) / BM, kB);  // 47 x 16 = 752 blocks
  vq_main<<<grid, NT, 0, stream>>>(z, W, out /*z_q*/, out + N_ZQ /*ind*/, ws);
  vq_finish<<<1, 1, 0, stream>>>(ws, out + N_ZQ + N_IND);
}

// Round 2
// 463.408 us; speedup vs baseline: 2.6920x; 2.6920x over previous
//
#include <hip/hip_runtime.h>
#include <math.h>

namespace {
constexpr int kB  = 16;
constexpr int kD  = 512;
constexpr int kL  = 3000;
constexpr int kNE = 1024;
constexpr int N_ZQ  = kB * kD * kL;   // 24576000
constexpr int N_IND = kB * kL;        // 48000
constexpr int MAXFLAGS = 48000;
constexpr float TAU = 0.02f;
}

typedef _Float16 half8 __attribute__((ext_vector_type(8)));
typedef float    f32x4 __attribute__((ext_vector_type(4)));

__device__ __forceinline__ void gl16(const void* g, void* l) {
  __builtin_amdgcn_global_load_lds(
      (const __attribute__((address_space(1))) unsigned int*)g,
      (__attribute__((address_space(3))) unsigned int*)l, 16, 0, 0);
}

__global__ void vq_init(double* loss, int* cnt) { loss[0] = 0.0; cnt[0] = 0; }

// ---- prepass: W[1024][512] f32 -> Wp[chunk][n][8 granules of 16B], hi/lo f16, slot-swizzled ----
__global__ void vq_prep_w(const float* __restrict__ W, char* __restrict__ Wp) {
  const int tid = threadIdx.x;
  const int n = blockIdx.x * 64 + (tid >> 2);
  const int g = tid & 3;
  const float* wr = W + (size_t)n * kD;
#pragma unroll 1
  for (int c = 0; c < 16; ++c) {
    half8 hi, lo;
#pragma unroll
    for (int e = 0; e < 8; ++e) {
      float x = wr[c * 32 + g * 8 + e];
      _Float16 h = (_Float16)x;
      hi[e] = h; lo[e] = (_Float16)(x - (float)h);
    }
    char* row = Wp + (((size_t)(c * kNE + n)) << 7);
    *(half8*)(row + ((g ^ (n & 7)) << 4))       = hi;
    *(half8*)(row + (((4 | g) ^ (n & 7)) << 4)) = lo;
  }
}

// ---- prepass: z[b][d][l] f32 -> zp[b][chunk][l][slots] (transpose + hi/lo + swizzle) ----
__global__ void vq_prep_z(const float* __restrict__ z, char* __restrict__ zp) {
  const int tid = threadIdx.x;
  const int ll = blockIdx.x * 64 + (tid >> 2);
  const int g  = tid & 3;
  const int b  = blockIdx.y;
  if (ll >= kL) return;
  const float* zb = z + (size_t)b * kD * kL + ll;
#pragma unroll 1
  for (int c = 0; c < 16; ++c) {
    half8 hi, lo;
#pragma unroll
    for (int e = 0; e < 8; ++e) {
      float x = zb[(size_t)(c * 32 + g * 8 + e) * kL];
      _Float16 h = (_Float16)x;
      hi[e] = h; lo[e] = (_Float16)(x - (float)h);
    }
    char* row = zp + (((size_t)(b * 16 + c) * kL + ll) << 7);
    *(half8*)(row + ((g ^ (ll & 7)) << 4))       = hi;
    *(half8*)(row + (((4 | g) ^ (ll & 7)) << 4)) = lo;
  }
}

// ---- main: logits via split-f16 MFMA, fused top-2 argmax ----
__global__ __launch_bounds__(256, 2) void vq_gemm(
    const char* __restrict__ Wp, const char* __restrict__ zp,
    float* __restrict__ ind, int* __restrict__ flagcnt, int* __restrict__ flags) {
  __shared__ union {
    struct { char W[256 * 128]; char Z[64 * 128]; } s;    // 40 KB
    struct { float v1[4][64]; int i1[4][64]; float v2[4][64]; } r;
  } u;

  const int tid  = threadIdx.x;
  const int w    = tid >> 6;
  const int lane = tid & 63;
  const int m    = lane & 15;
  const int g    = lane >> 4;
  const int b    = blockIdx.y;
  const int l0   = blockIdx.x * 64;

  float b1[4], b2[4]; int i1[4];
#pragma unroll
  for (int lt = 0; lt < 4; ++lt) { b1[lt] = -INFINITY; b2[lt] = -INFINITY; i1[lt] = 0; }

  const int sh = ((g ^ (m & 7)) << 4);         // hi slot byte offset within 128B row
  const int sl = ((((4 | g)) ^ (m & 7)) << 4); // lo slot

  for (int n0 = 0; n0 < kNE; n0 += 256) {
    f32x4 acc[4][4];
#pragma unroll
    for (int nt = 0; nt < 4; ++nt)
#pragma unroll
      for (int lt = 0; lt < 4; ++lt) acc[nt][lt] = (f32x4){0.f, 0.f, 0.f, 0.f};

#pragma unroll 1
    for (int c = 0; c < 16; ++c) {
      __syncthreads();
      // stage W chunk rows w*64..w*64+63 (linear, pre-swizzled)
      {
        const char* src = Wp + (((size_t)(c * kNE + n0 + w * 64)) << 7) + lane * 16;
        char* dst = u.s.W + (w * 64) * 128;
#pragma unroll
        for (int j = 0; j < 8; ++j) gl16(src + j * 1024, dst + j * 1024);
      }
      // stage z chunk rows w*16..w*16+15
      {
        const char* src = zp + (((size_t)(b * 16 + c) * kL + l0 + w * 16) << 7) + lane * 16;
        char* dst = u.s.Z + (w * 16) * 128;
        gl16(src, dst);
        gl16(src + 1024, dst + 1024);
      }
      __syncthreads();

      half8 aH[4], aL[4], bH[4], bL[4];
#pragma unroll
      for (int nt = 0; nt < 4; ++nt) {
        const char* rp = u.s.W + (w * 64 + nt * 16 + m) * 128;
        aH[nt] = *(const half8*)(rp + sh);
        aL[nt] = *(const half8*)(rp + sl);
      }
#pragma unroll
      for (int lt = 0; lt < 4; ++lt) {
        const char* rp = u.s.Z + (lt * 16 + m) * 128;
        bH[lt] = *(const half8*)(rp + sh);
        bL[lt] = *(const half8*)(rp + sl);
      }
#pragma unroll
      for (int nt = 0; nt < 4; ++nt)
#pragma unroll
        for (int lt = 0; lt < 4; ++lt) {
          acc[nt][lt] = __builtin_amdgcn_mfma_f32_16x16x32_f16(aH[nt], bH[lt], acc[nt][lt], 0, 0, 0);
          acc[nt][lt] = __builtin_amdgcn_mfma_f32_16x16x32_f16(aH[nt], bL[lt], acc[nt][lt], 0, 0, 0);
          acc[nt][lt] = __builtin_amdgcn_mfma_f32_16x16x32_f16(aL[nt], bH[lt], acc[nt][lt], 0, 0, 0);
        }
    }

    // running top-2 (n ascending within lane -> strict > keeps lowest index)
#pragma unroll
    for (int nt = 0; nt < 4; ++nt)
#pragma unroll
      for (int r = 0; r < 4; ++r) {
        const int n = n0 + w * 64 + nt * 16 + g * 4 + r;
#pragma unroll
        for (int lt = 0; lt < 4; ++lt) {
          float v = acc[nt][lt][r];
          if (v > b1[lt]) { b2[lt] = b1[lt]; b1[lt] = v; i1[lt] = n; }
          else if (v > b2[lt]) b2[lt] = v;
        }
      }
  }

  __syncthreads();  // all waves done with staging LDS before reuse

  // cross-lane reduce: lanes c, c+16, c+32, c+48 cover the 16 D-rows
#pragma unroll
  for (int lt = 0; lt < 4; ++lt) {
#pragma unroll
    for (int mk = 16; mk <= 32; mk <<= 1) {
      float o1 = __shfl_xor(b1[lt], mk);
      float o2 = __shfl_xor(b2[lt], mk);
      int   oi = __shfl_xor(i1[lt], mk);
      if (o1 > b1[lt] || (o1 == b1[lt] && oi < i1[lt])) {
        b2[lt] = fmaxf(b1[lt], o2); b1[lt] = o1; i1[lt] = oi;
      } else {
        b2[lt] = fmaxf(b2[lt], o1);
      }
    }
  }
  if (lane < 16) {
#pragma unroll
    for (int lt = 0; lt < 4; ++lt) {
      u.r.v1[w][lt * 16 + lane] = b1[lt];
      u.r.i1[w][lt * 16 + lane] = i1[lt];
      u.r.v2[w][lt * 16 + lane] = b2[lt];
    }
  }
  __syncthreads();
  if (tid < 64) {
    float v = u.r.v1[0][tid]; int i = u.r.i1[0][tid]; float v2 = u.r.v2[0][tid];
#pragma unroll
    for (int w2 = 1; w2 < 4; ++w2) {
      float ov = u.r.v1[w2][tid]; int oi = u.r.i1[w2][tid]; float ov2 = u.r.v2[w2][tid];
      if (ov > v || (ov == v && oi < i)) { v2 = fmaxf(v, ov2); v = ov; i = oi; }
      else v2 = fmaxf(v2, ov);
    }
    const int l = l0 + tid;
    if (l < kL) {
      ind[b * kL + l] = (float)i;
      if (v - v2 < TAU) {
        int p = atomicAdd(flagcnt, 1);
        if (p < MAXFLAGS) flags[p] = b * kL + l;
      }
    }
  }
}

// ---- exact f32 recheck of near-tie positions ----
__global__ void vq_recheck(const float* __restrict__ z, const float* __restrict__ W,
                           float* __restrict__ ind, const int* __restrict__ flags,
                           const int* __restrict__ cnt) {
  __shared__ float col[512];
  __shared__ float rv[256];
  __shared__ int   ri[256];
  const int tid = threadIdx.x;
  const int n_flags = min(*cnt, MAXFLAGS);
  for (int fi = blockIdx.x; fi < n_flags; fi += gridDim.x) {
    const int p = flags[fi];
    const int b = p / kL, l = p % kL;
    __syncthreads();
    for (int d = tid; d < kD; d += 256) col[d] = z[((size_t)b * kD + d) * kL + l];
    __syncthreads();
    float best = -INFINITY; int bi = 0;
    const float4* c4 = (const float4*)col;
#pragma unroll 1
    for (int r = 0; r < 4; ++r) {
      const int n = r * 256 + tid;
      const float4* wr = (const float4*)(W + (size_t)n * kD);
      float s = 0.f;
      for (int d4 = 0; d4 < 128; ++d4) {
        float4 a = wr[d4], bb = c4[d4];
        s = fmaf(a.x, bb.x, s); s = fmaf(a.y, bb.y, s);
        s = fmaf(a.z, bb.z, s); s = fmaf(a.w, bb.w, s);
      }
      if (s > best) { best = s; bi = n; }
    }
    rv[tid] = best; ri[tid] = bi;
    __syncthreads();
    for (int st = 128; st > 0; st >>= 1) {
      if (tid < st) {
        float ov = rv[tid + st]; int oi = ri[tid + st];
        if (ov > rv[tid] || (ov == rv[tid] && oi < ri[tid])) { rv[tid] = ov; ri[tid] = oi; }
      }
      __syncthreads();
    }
    if (tid == 0) ind[p] = (float)ri[0];
  }
}

// ---- epilogue: gather z_q, f64 loss ----
__global__ void vq_epilogue(const float* __restrict__ z, const float* __restrict__ W,
                            const float* __restrict__ ind, float* __restrict__ zq,
                            double* __restrict__ lossws) {
  __shared__ int    bidx[64];
  __shared__ double lred[256];
  const int tid = threadIdx.x;
  const int l0 = blockIdx.x * 64;
  const int b  = blockIdx.y;
  const size_t zb = (size_t)b * kD * kL;
  if (tid < 64) bidx[tid] = (l0 + tid < kL) ? (int)ind[b * kL + l0 + tid] : 0;
  __syncthreads();

  const int mvalid = kL - l0;
  double lsum = 0.0;
#pragma unroll 4
  for (int r = 0; r < 32; ++r) {
    const int flat = r * 256 + tid;
    const int d  = flat >> 4;
    const int m4 = (flat & 15) << 2;
    if (m4 < mvalid) {
      const size_t zi = zb + (size_t)d * kL + (l0 + m4);
      float4 zv = *(const float4*)(z + zi);
      float4 wv;
      wv.x = W[(size_t)bidx[m4 + 0] * kD + d];
      wv.y = W[(size_t)bidx[m4 + 1] * kD + d];
      wv.z = W[(size_t)bidx[m4 + 2] * kD + d];
      wv.w = W[(size_t)bidx[m4 + 3] * kD + d];
      *(float4*)(zq + zi) = wv;
      const float dx = wv.x - zv.x, dy = wv.y - zv.y;
      const float dz2 = wv.z - zv.z, dw = wv.w - zv.w;
      lsum += (double)dx * dx + (double)dy * dy + (double)dz2 * dz2 + (double)dw * dw;
    }
  }
  lred[tid] = lsum;
  __syncthreads();
  if (tid == 0) {
    double s = 0.0;
    for (int t = 0; t < 256; ++t) s += lred[t];
    atomicAdd(lossws, s);
  }
}

__global__ void vq_finish(const double* __restrict__ ws, float* __restrict__ out) {
  out[0] = (float)(ws[0] * 2.25 / (double)N_ZQ);
}

extern "C" void kernel_launch(void* const* d_in, const int* in_sizes, int n_in,
                              void* d_out, int out_size, void* d_ws, size_t ws_size,
                              hipStream_t stream) {
  const float* z = (const float*)d_in[0];
  const float* W = (const float*)d_in[1];
  float* out = (float*)d_out;
  char*  ws  = (char*)d_ws;

  double* loss    = (double*)ws;
  int*    flagcnt = (int*)(ws + 8);
  int*    flags   = (int*)(ws + 64);
  char*   Wp      = ws + (1 << 20);     // 2 MB at +1 MB
  char*   zp      = (char*)d_out;       // reuse z_q region (exact fit: 16*16*3000*128 B)
  float*  ind     = out + N_ZQ;
  float*  diff    = out + N_ZQ + N_IND;

  vq_init<<<1, 1, 0, stream>>>(loss, flagcnt);
  vq_prep_w<<<16, 256, 0, stream>>>(W, Wp);
  vq_prep_z<<<dim3(47, kB), 256, 0, stream>>>(z, zp);
  vq_gemm<<<dim3(47, kB), 256, 0, stream>>>(Wp, zp, ind, flagcnt, flags);
  vq_recheck<<<256, 256, 0, stream>>>(z, W, ind, flags, flagcnt);
  vq_epilogue<<<dim3(47, kB), 256, 0, stream>>>(z, W, ind, out, loss);
  vq_finish<<<1, 1, 0, stream>>>(loss, diff);
}